// Round 6
// baseline (4922.606 us; speedup 1.0000x reference)
//
#include <hip/hip_runtime.h>
#include <hip/hip_bf16.h>

#define D 256

// ---------------- zero f32 scratch ----------------
__global__ __launch_bounds__(256) void zero_kernel(float* p, int n) {
    int i = blockIdx.x * 256 + threadIdx.x;
    if (i < n) p[i] = 0.f;
}

// ---------------- score: ONE THREAD per edge, serial dot ----------------
__global__ __launch_bounds__(256) void score_kernel(
    const float* __restrict__ atom, const int* __restrict__ src, const int* __restrict__ dst,
    const float* __restrict__ W, const float* __restrict__ b,
    const float* __restrict__ g, const float* __restrict__ bb,
    const float* __restrict__ mn, const float* __restrict__ vr,
    float* __restrict__ s_edge, int E)
{
    int e = blockIdx.x * 256 + threadIdx.x;
    if (e >= E) return;
    const float* as = atom + (size_t)src[e] * D;
    const float* ad = atom + (size_t)dst[e] * D;
    float acc = 0.f;
    for (int k = 0; k < D; k += 4) {
        float4 a = *(const float4*)(as + k);
        float4 w0 = *(const float4*)(W + k);
        float4 c = *(const float4*)(ad + k);
        float4 w1 = *(const float4*)(W + D + k);
        acc += a.x * w0.x + a.y * w0.y + a.z * w0.z + a.w * w0.w
             + c.x * w1.x + c.y * w1.y + c.z * w1.z + c.w * w1.w;
    }
    float x = acc + b[0];
    x = (x - mn[0]) * rsqrtf(vr[0] + 1e-6f) * g[0] + bb[0];
    x = x > 0.f ? x : 0.01f * x;        // leaky_relu(0.01)
    s_edge[e] = x;
}

// ---------------- denom[a] = sum over edges with src=a of exp(s) (atomic) ----------------
__global__ __launch_bounds__(256) void denom_kernel(
    const int* __restrict__ src, const float* __restrict__ s_edge, float* denom, int E)
{
    int e = blockIdx.x * 256 + threadIdx.x;
    if (e < E) atomicAdd(&denom[src[e]], __expf(s_edge[e]));
}

// ---------------- hA = BN(atom @ W_att^T + b_att), VALU f32 ----------------
__global__ __launch_bounds__(256) void hA_valu(
    const float* __restrict__ atom, const float* __restrict__ W,
    const float* __restrict__ bias,
    const float* __restrict__ g, const float* __restrict__ bb,
    const float* __restrict__ mn, const float* __restrict__ vr,
    float* __restrict__ hA, int N)
{
    __shared__ float sa[16][D];
    int c = threadIdx.x;
    int a0 = blockIdx.x * 16;
    #pragma unroll
    for (int r = 0; r < 16; r++) {
        int row = a0 + r;
        if (row < N) sa[r][c] = atom[(size_t)row * D + c];
    }
    __syncthreads();
    const float* wc = W + (size_t)c * D;
    float scale = rsqrtf(vr[c] + 1e-6f) * g[c];
    float shift = bb[c] - mn[c] * scale;
    float bi = bias[c];
    for (int r = 0; r < 16; r++) {
        int row = a0 + r;
        if (row >= N) break;
        float acc = 0.f;
        #pragma unroll 8
        for (int k = 0; k < D; k++) acc += sa[r][k] * wc[k];
        hA[(size_t)row * D + c] = (acc + bi) * scale + shift;
    }
}

// ---------------- ctx[src[e]] += attn_e * hA[dst[e]]  (wave per edge, f32 atomics) ----------------
__global__ __launch_bounds__(256) void ctx_kernel(
    const int* __restrict__ src, const int* __restrict__ dst,
    const float* __restrict__ s_edge, const float* __restrict__ denom,
    const float* __restrict__ hA, float* ctx, int E)
{
    int w = (blockIdx.x * blockDim.x + threadIdx.x) >> 6;
    int lane = threadIdx.x & 63;
    if (w >= E) return;
    int s = src[w], dd = dst[w];
    float at = __expf(s_edge[w]) / (denom[s] + 1e-8f);
    float4 h = *(const float4*)(hA + (size_t)dd * D + lane * 4);
    float* cp = ctx + (size_t)s * D + lane * 4;
    atomicAdd(cp + 0, at * h.x);
    atomicAdd(cp + 1, at * h.y);
    atomicAdd(cp + 2, at * h.z);
    atomicAdd(cp + 3, at * h.w);
}

// ---------------- elu in place ----------------
__global__ __launch_bounds__(256) void elu_kernel(float* p, int n) {
    int i = blockIdx.x * 256 + threadIdx.x;
    if (i < n) {
        float x = p[i];
        p[i] = x > 0.f ? x : __expf(x) - 1.f;
    }
}

// ---------------- fused GRU cell, VALU f32; OUTPUT FLOAT32 ----------------
__global__ __launch_bounds__(256) void gru_valu(
    const float* __restrict__ ctx, const float* __restrict__ atom,
    const float* __restrict__ W_ih, const float* __restrict__ W_hh,
    const float* __restrict__ b_ih, const float* __restrict__ b_hh,
    float* __restrict__ out, int N)
{
    __shared__ float sc[16][D];
    __shared__ float sa[16][D];
    int c = threadIdx.x;
    int a0 = blockIdx.x * 16;
    #pragma unroll
    for (int r = 0; r < 16; r++) {
        int row = a0 + r;
        if (row < N) {
            sc[r][c] = ctx[(size_t)row * D + c];
            sa[r][c] = atom[(size_t)row * D + c];
        }
    }
    __syncthreads();
    const float* wir = W_ih + (size_t)c * D;
    const float* wiz = W_ih + (size_t)(c + 256) * D;
    const float* win = W_ih + (size_t)(c + 512) * D;
    const float* whr = W_hh + (size_t)c * D;
    const float* whz = W_hh + (size_t)(c + 256) * D;
    const float* whn = W_hh + (size_t)(c + 512) * D;
    float bir = b_ih[c], biz = b_ih[c + 256], bin_ = b_ih[c + 512];
    float bhr = b_hh[c], bhz = b_hh[c + 256], bhn = b_hh[c + 512];
    for (int r = 0; r < 16; r++) {
        int row = a0 + r;
        if (row >= N) break;
        float ir = 0.f, iz = 0.f, inr = 0.f, hr = 0.f, hz = 0.f, hn = 0.f;
        #pragma unroll 4
        for (int k = 0; k < D; k++) {
            float x = sc[r][k], h = sa[r][k];
            ir += x * wir[k]; iz += x * wiz[k]; inr += x * win[k];
            hr += h * whr[k]; hz += h * whz[k]; hn += h * whn[k];
        }
        float rr = 1.f / (1.f + __expf(-(ir + bir + hr + bhr)));
        float zz = 1.f / (1.f + __expf(-(iz + biz + hz + bhz)));
        float nn = tanhf(inr + bin_ + rr * (hn + bhn));
        out[(size_t)row * D + c] = (1.f - zz) * nn + zz * sa[r][c];
    }
}

extern "C" void kernel_launch(void* const* d_in, const int* in_sizes, int n_in,
                              void* d_out, int out_size, void* d_ws, size_t ws_size,
                              hipStream_t stream) {
    const float* atom    = (const float*)d_in[0];
    const int*   bond    = (const int*)d_in[1];
    const float* W_align = (const float*)d_in[2];
    const float* b_align = (const float*)d_in[3];
    const float* bn_a_g  = (const float*)d_in[4];
    const float* bn_a_b  = (const float*)d_in[5];
    const float* bn_a_m  = (const float*)d_in[6];
    const float* bn_a_v  = (const float*)d_in[7];
    const float* W_att   = (const float*)d_in[8];
    const float* b_att   = (const float*)d_in[9];
    const float* bn_t_g  = (const float*)d_in[10];
    const float* bn_t_b  = (const float*)d_in[11];
    const float* bn_t_m  = (const float*)d_in[12];
    const float* bn_t_v  = (const float*)d_in[13];
    const float* W_ih    = (const float*)d_in[14];
    const float* W_hh    = (const float*)d_in[15];
    const float* b_ih    = (const float*)d_in[16];
    const float* b_hh    = (const float*)d_in[17];

    int N = in_sizes[0] / D;
    int E = in_sizes[1] / 2;
    const int* src = bond;
    const int* dst = bond + E;

    char* w = (char*)d_ws;
    size_t o = 0;
    auto alloc = [&](size_t bytes) {
        void* p = w + o;
        o = (o + bytes + 255) & ~(size_t)255;
        return p;
    };
    float* s_edge = (float*)alloc((size_t)E * 4);
    float* denom  = (float*)alloc((size_t)N * 4);
    float* hA     = (float*)alloc((size_t)N * D * 4);
    float* ctx    = (float*)alloc((size_t)N * D * 4);

    int ND = N * D;
    zero_kernel<<<(N + 255) / 256, 256, 0, stream>>>(denom, N);
    zero_kernel<<<(ND + 255) / 256, 256, 0, stream>>>(ctx, ND);
    score_kernel<<<(E + 255) / 256, 256, 0, stream>>>(
        atom, src, dst, W_align, b_align, bn_a_g, bn_a_b, bn_a_m, bn_a_v, s_edge, E);
    denom_kernel<<<(E + 255) / 256, 256, 0, stream>>>(src, s_edge, denom, E);
    hA_valu<<<(N + 15) / 16, 256, 0, stream>>>(
        atom, W_att, b_att, bn_t_g, bn_t_b, bn_t_m, bn_t_v, hA, N);
    ctx_kernel<<<((size_t)E * 64 + 255) / 256, 256, 0, stream>>>(
        src, dst, s_edge, denom, hA, ctx, E);
    elu_kernel<<<(ND + 255) / 256, 256, 0, stream>>>(ctx, ND);
    gru_valu<<<(N + 15) / 16, 256, 0, stream>>>(
        ctx, atom, W_ih, W_hh, b_ih, b_hh, (float*)d_out, N);
}

// Round 7
// 312.991 us; speedup vs baseline: 15.7276x; 15.7276x over previous
//
#include <hip/hip_runtime.h>
#include <hip/hip_bf16.h>

#define D 256

typedef __attribute__((ext_vector_type(8))) short bf16x8;
typedef __attribute__((ext_vector_type(4))) short s16x4;
typedef __attribute__((ext_vector_type(4))) float f32x4;

#define MFMA __builtin_amdgcn_mfma_f32_16x16x32_bf16

__device__ __forceinline__ float s2f(short u) {
    union { unsigned int i; float f; } c;
    c.i = ((unsigned int)(unsigned short)u) << 16;
    return c.f;
}
__device__ __forceinline__ short f2s(float f) {
    union { float f; unsigned int u; } c; c.f = f;
    unsigned int u = c.u;
    u += 0x7fffu + ((u >> 16) & 1u);
    return (short)(u >> 16);
}

// ---------------- f32 -> bf16 conversion (n4 = n/4) ----------------
__global__ __launch_bounds__(256) void cvt_kernel(const float* __restrict__ in, short* __restrict__ out, int n4) {
    int i = blockIdx.x * 256 + threadIdx.x;
    if (i < n4) {
        float4 v = ((const float4*)in)[i];
        s16x4 o; o[0] = f2s(v.x); o[1] = f2s(v.y); o[2] = f2s(v.z); o[3] = f2s(v.w);
        ((s16x4*)out)[i] = o;
    }
}

// ---------------- zero CSR scratch ----------------
__global__ __launch_bounds__(256) void init_kernel(int* cnt, int* cursor, int N) {
    int i = blockIdx.x * 256 + threadIdx.x;
    if (i < N) { cnt[i] = 0; cursor[i] = 0; }
}

// ---------------- histogram of src ----------------
__global__ __launch_bounds__(256) void count_kernel(const int* __restrict__ src, int* cnt, int E) {
    int e = blockIdx.x * 256 + threadIdx.x;
    if (e < E) atomicAdd(&cnt[src[e]], 1);
}

// ---------------- exclusive scan (single block) ----------------
__global__ __launch_bounds__(1024) void scan_kernel(const int* __restrict__ cnt, int* __restrict__ off, int N) {
    __shared__ int buf[1024];
    __shared__ int carry;
    int t = threadIdx.x;
    if (t == 0) carry = 0;
    __syncthreads();
    for (int start = 0; start < N; start += 1024) {
        int i = start + t;
        int v = (i < N) ? cnt[i] : 0;
        buf[t] = v;
        __syncthreads();
        for (int d = 1; d < 1024; d <<= 1) {
            int x = (t >= d) ? buf[t - d] : 0;
            __syncthreads();
            buf[t] += x;
            __syncthreads();
        }
        int incl = buf[t];
        int base = carry;
        if (i < N) off[i] = base + incl - v;
        int total = buf[1023];
        __syncthreads();
        if (t == 0) carry = base + total;
        __syncthreads();
    }
    if (t == 0) off[N] = carry;
}

// ---------------- fill edge lists ----------------
__global__ __launch_bounds__(256) void fill_kernel(const int* __restrict__ src, const int* __restrict__ off,
                                                   int* cursor, int* el, int E) {
    int e = blockIdx.x * 256 + threadIdx.x;
    if (e < E) {
        int s = src[e];
        int p = atomicAdd(&cursor[s], 1);
        el[off[s] + p] = e;
    }
}

// ---------------- per-edge align score (wave per edge), f32 ----------------
__global__ __launch_bounds__(256) void score_kernel(
    const float* __restrict__ atom, const int* __restrict__ src, const int* __restrict__ dst,
    const float* __restrict__ W_align, const float* __restrict__ b_align,
    const float* __restrict__ g, const float* __restrict__ bb,
    const float* __restrict__ mn, const float* __restrict__ vr,
    float* __restrict__ s_edge, int E)
{
    int w = (blockIdx.x * blockDim.x + threadIdx.x) >> 6;
    int lane = threadIdx.x & 63;
    if (w >= E) return;
    int s = src[w], dd = dst[w];
    float4 a0 = *(const float4*)(atom + (size_t)s * D + lane * 4);
    float4 a1 = *(const float4*)(atom + (size_t)dd * D + lane * 4);
    float4 w0 = *(const float4*)(W_align + lane * 4);
    float4 w1 = *(const float4*)(W_align + D + lane * 4);
    float acc = a0.x * w0.x + a0.y * w0.y + a0.z * w0.z + a0.w * w0.w
              + a1.x * w1.x + a1.y * w1.y + a1.z * w1.z + a1.w * w1.w;
    #pragma unroll
    for (int o = 32; o > 0; o >>= 1) acc += __shfl_xor(acc, o, 64);
    if (lane == 0) {
        float x = acc + b_align[0];
        x = (x - mn[0]) * rsqrtf(vr[0] + 1e-6f) * g[0] + bb[0];
        x = x > 0.f ? x : 0.01f * x;               // leaky_relu(0.01)
        s_edge[w] = x;
    }
}

// ---------------- segment softmax (wave per atom) ----------------
__global__ __launch_bounds__(256) void softmax_kernel(
    const int* __restrict__ off, const int* __restrict__ el,
    const float* __restrict__ s_edge, float* __restrict__ attn, int N)
{
    int w = (blockIdx.x * blockDim.x + threadIdx.x) >> 6;
    int lane = threadIdx.x & 63;
    if (w >= N) return;
    int beg = off[w], end = off[w + 1];
    float m = -INFINITY;
    for (int j = beg + lane; j < end; j += 64) m = fmaxf(m, s_edge[el[j]]);
    #pragma unroll
    for (int o = 32; o > 0; o >>= 1) m = fmaxf(m, __shfl_xor(m, o, 64));
    float sum = 0.f;
    for (int j = beg + lane; j < end; j += 64) sum += __expf(s_edge[el[j]] - m);
    #pragma unroll
    for (int o = 32; o > 0; o >>= 1) sum += __shfl_xor(sum, o, 64);
    float inv = 1.f / (sum + 1e-8f);
    for (int j = beg + lane; j < end; j += 64) {
        int e = el[j];
        attn[e] = __expf(s_edge[e] - m) * inv;
    }
}

// ---------------- hA = BN(atom @ W_att^T + b_att), MFMA, bf16 out ----------------
__global__ __launch_bounds__(256) void hA_kernel(
    const short* __restrict__ atom_bf, const short* __restrict__ W_bf,
    const float* __restrict__ bias,
    const float* __restrict__ g, const float* __restrict__ bb,
    const float* __restrict__ mn, const float* __restrict__ vr,
    short* __restrict__ hA, int N)
{
    int wave = threadIdx.x >> 6, lane = threadIdx.x & 63;
    int quad = lane >> 4, l15 = lane & 15;
    int m0 = blockIdx.x * 64 + wave * 16;
    int c0 = blockIdx.y * 64;
    int arow = m0 + l15; if (arow > N - 1) arow = N - 1;
    const short* ap = atom_bf + (size_t)arow * D + quad * 8;
    const short* wp = W_bf + (size_t)(c0 + l15) * D + quad * 8;
    f32x4 ac0 = {0,0,0,0}, ac1 = {0,0,0,0}, ac2 = {0,0,0,0}, ac3 = {0,0,0,0};
    #pragma unroll
    for (int k = 0; k < D; k += 32) {
        bf16x8 a  = *(const bf16x8*)(ap + k);
        bf16x8 b0 = *(const bf16x8*)(wp + k);
        bf16x8 b1 = *(const bf16x8*)(wp + 16 * D + k);
        bf16x8 b2 = *(const bf16x8*)(wp + 32 * D + k);
        bf16x8 b3 = *(const bf16x8*)(wp + 48 * D + k);
        ac0 = MFMA(a, b0, ac0, 0, 0, 0);
        ac1 = MFMA(a, b1, ac1, 0, 0, 0);
        ac2 = MFMA(a, b2, ac2, 0, 0, 0);
        ac3 = MFMA(a, b3, ac3, 0, 0, 0);
    }
    f32x4 accs[4] = {ac0, ac1, ac2, ac3};
    #pragma unroll
    for (int t = 0; t < 4; t++) {
        int col = c0 + t * 16 + l15;
        float sc = rsqrtf(vr[col] + 1e-6f) * g[col];
        float sh = bb[col] - mn[col] * sc;
        float bi = bias[col];
        #pragma unroll
        for (int r = 0; r < 4; r++) {
            int row = m0 + quad * 4 + r;
            if (row < N) hA[(size_t)row * D + col] = f2s((accs[t][r] + bi) * sc + sh);
        }
    }
}

// ---------------- context = ELU(sum attn*hA[dst]) (wave per atom), bf16 out ----------------
__global__ __launch_bounds__(256) void aggregate_kernel(
    const int* __restrict__ off, const int* __restrict__ el,
    const int* __restrict__ dst, const float* __restrict__ attn,
    const short* __restrict__ hA, short* __restrict__ ctx, int N)
{
    int w = (blockIdx.x * blockDim.x + threadIdx.x) >> 6;
    int lane = threadIdx.x & 63;
    if (w >= N) return;
    int beg = off[w], end = off[w + 1];
    float a0 = 0.f, a1 = 0.f, a2 = 0.f, a3 = 0.f;
    for (int j = beg; j < end; j++) {
        int e = el[j];
        float t = attn[e];
        s16x4 h = *(const s16x4*)(hA + (size_t)dst[e] * D + lane * 4);
        a0 += t * s2f(h[0]); a1 += t * s2f(h[1]);
        a2 += t * s2f(h[2]); a3 += t * s2f(h[3]);
    }
    a0 = a0 > 0.f ? a0 : __expf(a0) - 1.f;
    a1 = a1 > 0.f ? a1 : __expf(a1) - 1.f;
    a2 = a2 > 0.f ? a2 : __expf(a2) - 1.f;
    a3 = a3 > 0.f ? a3 : __expf(a3) - 1.f;
    s16x4 o; o[0] = f2s(a0); o[1] = f2s(a1); o[2] = f2s(a2); o[3] = f2s(a3);
    *(s16x4*)(ctx + (size_t)w * D + lane * 4) = o;
}

// ---------------- fused GRU cell, MFMA; OUTPUT FLOAT32 ----------------
__global__ __launch_bounds__(256) void gru_kernel(
    const short* __restrict__ ctx, const short* __restrict__ atom_bf,
    const float* __restrict__ atom_f,
    const short* __restrict__ W_ih, const short* __restrict__ W_hh,
    const float* __restrict__ b_ih, const float* __restrict__ b_hh,
    float* __restrict__ out, int N)
{
    int wave = threadIdx.x >> 6, lane = threadIdx.x & 63;
    int quad = lane >> 4, l15 = lane & 15;
    int m0 = blockIdx.x * 64 + wave * 16;
    int c0 = blockIdx.y * 16;
    int arow = m0 + l15; if (arow > N - 1) arow = N - 1;
    const short* cp = ctx + (size_t)arow * D + quad * 8;
    const short* ap = atom_bf + (size_t)arow * D + quad * 8;
    const short* wi = W_ih + (size_t)(c0 + l15) * D + quad * 8;
    const short* wh = W_hh + (size_t)(c0 + l15) * D + quad * 8;
    f32x4 ir = {0,0,0,0}, iz = {0,0,0,0}, in_ = {0,0,0,0};
    f32x4 hr = {0,0,0,0}, hz = {0,0,0,0}, hn = {0,0,0,0};
    #pragma unroll
    for (int k = 0; k < D; k += 32) {
        bf16x8 a1 = *(const bf16x8*)(cp + k);
        bf16x8 a2 = *(const bf16x8*)(ap + k);
        bf16x8 bir = *(const bf16x8*)(wi + k);
        bf16x8 biz = *(const bf16x8*)(wi + 256 * D + k);
        bf16x8 bin = *(const bf16x8*)(wi + 512 * D + k);
        bf16x8 bhr = *(const bf16x8*)(wh + k);
        bf16x8 bhz = *(const bf16x8*)(wh + 256 * D + k);
        bf16x8 bhn = *(const bf16x8*)(wh + 512 * D + k);
        ir  = MFMA(a1, bir, ir, 0, 0, 0);
        iz  = MFMA(a1, biz, iz, 0, 0, 0);
        in_ = MFMA(a1, bin, in_, 0, 0, 0);
        hr  = MFMA(a2, bhr, hr, 0, 0, 0);
        hz  = MFMA(a2, bhz, hz, 0, 0, 0);
        hn  = MFMA(a2, bhn, hn, 0, 0, 0);
    }
    int col = c0 + l15;
    float bir_s = b_ih[col], biz_s = b_ih[col + 256], bin_s = b_ih[col + 512];
    float bhr_s = b_hh[col], bhz_s = b_hh[col + 256], bhn_s = b_hh[col + 512];
    #pragma unroll
    for (int r = 0; r < 4; r++) {
        int row = m0 + quad * 4 + r;
        if (row < N) {
            float rr = 1.f / (1.f + __expf(-(ir[r] + bir_s + hr[r] + bhr_s)));
            float zz = 1.f / (1.f + __expf(-(iz[r] + biz_s + hz[r] + bhz_s)));
            float nn = tanhf(in_[r] + bin_s + rr * (hn[r] + bhn_s));
            float at = atom_f[(size_t)row * D + col];
            out[(size_t)row * D + col] = (1.f - zz) * nn + zz * at;
        }
    }
}

extern "C" void kernel_launch(void* const* d_in, const int* in_sizes, int n_in,
                              void* d_out, int out_size, void* d_ws, size_t ws_size,
                              hipStream_t stream) {
    const float* atom    = (const float*)d_in[0];
    const int*   bond    = (const int*)d_in[1];
    const float* W_align = (const float*)d_in[2];
    const float* b_align = (const float*)d_in[3];
    const float* bn_a_g  = (const float*)d_in[4];
    const float* bn_a_b  = (const float*)d_in[5];
    const float* bn_a_m  = (const float*)d_in[6];
    const float* bn_a_v  = (const float*)d_in[7];
    const float* W_att   = (const float*)d_in[8];
    const float* b_att   = (const float*)d_in[9];
    const float* bn_t_g  = (const float*)d_in[10];
    const float* bn_t_b  = (const float*)d_in[11];
    const float* bn_t_m  = (const float*)d_in[12];
    const float* bn_t_v  = (const float*)d_in[13];
    const float* W_ih    = (const float*)d_in[14];
    const float* W_hh    = (const float*)d_in[15];
    const float* b_ih    = (const float*)d_in[16];
    const float* b_hh    = (const float*)d_in[17];

    int N = in_sizes[0] / D;
    int E = in_sizes[1] / 2;
    const int* src = bond;
    const int* dst = bond + E;

    char* w = (char*)d_ws;
    size_t o = 0;
    auto alloc = [&](size_t bytes) {
        void* p = w + o;
        o = (o + bytes + 255) & ~(size_t)255;
        return p;
    };
    int*   cnt     = (int*)alloc((size_t)N * 4);
    int*   cursor  = (int*)alloc((size_t)N * 4);
    int*   offv    = (int*)alloc((size_t)(N + 1) * 4);
    int*   el      = (int*)alloc((size_t)E * 4);
    float* s_edge  = (float*)alloc((size_t)E * 4);
    float* attn    = (float*)alloc((size_t)E * 4);
    short* hA      = (short*)alloc((size_t)N * D * 2);
    short* ctx     = (short*)alloc((size_t)N * D * 2);
    short* atom_bf = (short*)alloc((size_t)N * D * 2);
    short* Watt_bf = (short*)alloc((size_t)D * D * 2);
    short* Wih_bf  = (short*)alloc((size_t)3 * D * D * 2);
    short* Whh_bf  = (short*)alloc((size_t)3 * D * D * 2);

    int nA = N * D / 4, nW = D * D / 4, nG = 3 * D * D / 4;
    cvt_kernel<<<(nA + 255) / 256, 256, 0, stream>>>(atom, atom_bf, nA);
    cvt_kernel<<<(nW + 255) / 256, 256, 0, stream>>>(W_att, Watt_bf, nW);
    cvt_kernel<<<(nG + 255) / 256, 256, 0, stream>>>(W_ih, Wih_bf, nG);
    cvt_kernel<<<(nG + 255) / 256, 256, 0, stream>>>(W_hh, Whh_bf, nG);

    init_kernel<<<(N + 255) / 256, 256, 0, stream>>>(cnt, cursor, N);
    count_kernel<<<(E + 255) / 256, 256, 0, stream>>>(src, cnt, E);
    scan_kernel<<<1, 1024, 0, stream>>>(cnt, offv, N);
    fill_kernel<<<(E + 255) / 256, 256, 0, stream>>>(src, offv, cursor, el, E);
    score_kernel<<<(E * 64 + 255) / 256, 256, 0, stream>>>(
        atom, src, dst, W_align, b_align, bn_a_g, bn_a_b, bn_a_m, bn_a_v, s_edge, E);
    softmax_kernel<<<((size_t)N * 64 + 255) / 256, 256, 0, stream>>>(offv, el, s_edge, attn, N);
    hA_kernel<<<dim3((N + 63) / 64, D / 64), 256, 0, stream>>>(
        atom_bf, Watt_bf, b_att, bn_t_g, bn_t_b, bn_t_m, bn_t_v, hA, N);
    aggregate_kernel<<<((size_t)N * 64 + 255) / 256, 256, 0, stream>>>(offv, el, dst, attn, hA, ctx, N);
    gru_kernel<<<dim3((N + 63) / 64, D / 16), 256, 0, stream>>>(
        ctx, atom_bf, atom, Wih_bf, Whh_bf, b_ih, b_hh, (float*)d_out, N);
}

// Round 8
// 267.608 us; speedup vs baseline: 18.3948x; 1.1696x over previous
//
#include <hip/hip_runtime.h>
#include <hip/hip_bf16.h>

#define D 256

typedef __attribute__((ext_vector_type(8))) short bf16x8;
typedef __attribute__((ext_vector_type(4))) short s16x4;
typedef __attribute__((ext_vector_type(4))) float f32x4;

#define MFMA __builtin_amdgcn_mfma_f32_16x16x32_bf16

__device__ __forceinline__ float s2f(short u) {
    union { unsigned int i; float f; } c;
    c.i = ((unsigned int)(unsigned short)u) << 16;
    return c.f;
}
__device__ __forceinline__ short f2s(float f) {
    union { float f; unsigned int u; } c; c.f = f;
    unsigned int u = c.u;
    u += 0x7fffu + ((u >> 16) & 1u);
    return (short)(u >> 16);
}

// ---------------- f32 -> bf16 conversion (n4 = n/4) ----------------
__global__ __launch_bounds__(256) void cvt_kernel(const float* __restrict__ in, short* __restrict__ out, int n4) {
    int i = blockIdx.x * 256 + threadIdx.x;
    if (i < n4) {
        float4 v = ((const float4*)in)[i];
        s16x4 o; o[0] = f2s(v.x); o[1] = f2s(v.y); o[2] = f2s(v.z); o[3] = f2s(v.w);
        ((s16x4*)out)[i] = o;
    }
}

// ---------------- per-atom align projections with BN folded in ----------------
// p0p[n] = A*(atom[n]·W0 + b_align) + (bb - A*mn);  p1p[n] = A*(atom[n]·W1)
// so s_edge = leaky(p0p[src] + p1p[dst])
__global__ __launch_bounds__(256) void p0p1_kernel(
    const float* __restrict__ atom, const float* __restrict__ W_align,
    const float* __restrict__ b_align,
    const float* __restrict__ g, const float* __restrict__ bb,
    const float* __restrict__ mn, const float* __restrict__ vr,
    float* __restrict__ p0p, float* __restrict__ p1p, int N)
{
    int w = (blockIdx.x * blockDim.x + threadIdx.x) >> 6;
    int lane = threadIdx.x & 63;
    if (w >= N) return;
    float4 a  = *(const float4*)(atom + (size_t)w * D + lane * 4);
    float4 w0 = *(const float4*)(W_align + lane * 4);
    float4 w1 = *(const float4*)(W_align + D + lane * 4);
    float d0 = a.x * w0.x + a.y * w0.y + a.z * w0.z + a.w * w0.w;
    float d1 = a.x * w1.x + a.y * w1.y + a.z * w1.z + a.w * w1.w;
    #pragma unroll
    for (int o = 32; o > 0; o >>= 1) {
        d0 += __shfl_xor(d0, o, 64);
        d1 += __shfl_xor(d1, o, 64);
    }
    if (lane == 0) {
        float A = rsqrtf(vr[0] + 1e-6f) * g[0];
        p0p[w] = A * (d0 + b_align[0]) + bb[0] - A * mn[0];
        p1p[w] = A * d1;
    }
}

// ---------------- zero CSR scratch ----------------
__global__ __launch_bounds__(256) void init_kernel(int* cnt, int* cursor, int N) {
    int i = blockIdx.x * 256 + threadIdx.x;
    if (i < N) { cnt[i] = 0; cursor[i] = 0; }
}

// ---------------- histogram of src ----------------
__global__ __launch_bounds__(256) void count_kernel(const int* __restrict__ src, int* cnt, int E) {
    int e = blockIdx.x * 256 + threadIdx.x;
    if (e < E) atomicAdd(&cnt[src[e]], 1);
}

// ---------------- exclusive scan, serial-chunk + 256-scan (single block) ----------------
__global__ __launch_bounds__(256) void scan_kernel(const int* __restrict__ cnt, int* __restrict__ off, int N) {
    __shared__ int sums[256];
    int t = threadIdx.x;
    int CH = (N + 255) / 256;
    int beg = t * CH;
    int end = beg + CH; if (end > N) end = N;
    int s = 0;
    for (int i = beg; i < end; i++) s += cnt[i];
    sums[t] = s;
    __syncthreads();
    for (int d = 1; d < 256; d <<= 1) {
        int x = (t >= d) ? sums[t - d] : 0;
        __syncthreads();
        sums[t] += x;
        __syncthreads();
    }
    int run = (t > 0) ? sums[t - 1] : 0;
    for (int i = beg; i < end; i++) { off[i] = run; run += cnt[i]; }
    if (end == N) off[N] = run;   // threads past the end all write the total (same value)
}

// ---------------- fill dst-valued edge lists ----------------
__global__ __launch_bounds__(256) void fill_kernel(const int* __restrict__ src, const int* __restrict__ dst,
                                                   const int* __restrict__ off, int* cursor, int* dlist, int E) {
    int e = blockIdx.x * 256 + threadIdx.x;
    if (e < E) {
        int s = src[e];
        int p = atomicAdd(&cursor[s], 1);
        dlist[off[s] + p] = dst[e];
    }
}

// ---------------- hA = BN(atom @ W_att^T + b_att), MFMA, XCD-swizzled, bf16 out ----------------
__global__ __launch_bounds__(256) void hA_kernel(
    const short* __restrict__ atom_bf, const short* __restrict__ W_bf,
    const float* __restrict__ bias,
    const float* __restrict__ g, const float* __restrict__ bb,
    const float* __restrict__ mn, const float* __restrict__ vr,
    short* __restrict__ hA, int N, int NB)
{
    // swizzle: all 4 col-blocks of an atom-group land on the same XCD (heuristic bi%8)
    int bi = blockIdx.x;
    int xcd = bi & 7, rest = bi >> 3;
    int cb = rest & 3, gh = rest >> 2;
    int gg = gh * 8 + xcd;
    if (gg >= NB) return;
    int wave = threadIdx.x >> 6, lane = threadIdx.x & 63;
    int quad = lane >> 4, l15 = lane & 15;
    int m0 = gg * 64 + wave * 16;
    int c0 = cb * 64;
    int arow = m0 + l15; if (arow > N - 1) arow = N - 1;
    const short* ap = atom_bf + (size_t)arow * D + quad * 8;
    const short* wp = W_bf + (size_t)(c0 + l15) * D + quad * 8;
    f32x4 ac0 = {0,0,0,0}, ac1 = {0,0,0,0}, ac2 = {0,0,0,0}, ac3 = {0,0,0,0};
    #pragma unroll
    for (int k = 0; k < D; k += 32) {
        bf16x8 a  = *(const bf16x8*)(ap + k);
        bf16x8 b0 = *(const bf16x8*)(wp + k);
        bf16x8 b1 = *(const bf16x8*)(wp + 16 * D + k);
        bf16x8 b2 = *(const bf16x8*)(wp + 32 * D + k);
        bf16x8 b3 = *(const bf16x8*)(wp + 48 * D + k);
        ac0 = MFMA(a, b0, ac0, 0, 0, 0);
        ac1 = MFMA(a, b1, ac1, 0, 0, 0);
        ac2 = MFMA(a, b2, ac2, 0, 0, 0);
        ac3 = MFMA(a, b3, ac3, 0, 0, 0);
    }
    f32x4 accs[4] = {ac0, ac1, ac2, ac3};
    #pragma unroll
    for (int t = 0; t < 4; t++) {
        int col = c0 + t * 16 + l15;
        float sc = rsqrtf(vr[col] + 1e-6f) * g[col];
        float sh = bb[col] - mn[col] * sc;
        float bi_ = bias[col];
        #pragma unroll
        for (int r = 0; r < 4; r++) {
            int row = m0 + quad * 4 + r;
            if (row < N) hA[(size_t)row * D + col] = f2s((accs[t][r] + bi_) * sc + sh);
        }
    }
}

// ---------------- fused score+softmax+aggregate (wave per atom), bf16 ctx out ----------------
__global__ __launch_bounds__(256) void agg_kernel(
    const int* __restrict__ off, const int* __restrict__ dlist,
    const float* __restrict__ p0p, const float* __restrict__ p1p,
    const short* __restrict__ hA, short* __restrict__ ctx, int N)
{
    int w = (blockIdx.x * blockDim.x + threadIdx.x) >> 6;
    int lane = threadIdx.x & 63;
    if (w >= N) return;
    int beg = off[w], end = off[w + 1];
    float u = p0p[w];
    // pass 1: segment max of leaky(u + p1p[d])
    float m = -INFINITY;
    for (int j = beg + lane; j < end; j += 64) {
        float x = u + p1p[dlist[j]];
        x = x > 0.f ? x : 0.01f * x;
        m = fmaxf(m, x);
    }
    #pragma unroll
    for (int o = 32; o > 0; o >>= 1) m = fmaxf(m, __shfl_xor(m, o, 64));
    // pass 2: sum of exp
    float sum = 0.f;
    for (int j = beg + lane; j < end; j += 64) {
        float x = u + p1p[dlist[j]];
        x = x > 0.f ? x : 0.01f * x;
        sum += __expf(x - m);
    }
    #pragma unroll
    for (int o = 32; o > 0; o >>= 1) sum += __shfl_xor(sum, o, 64);
    float inv = 1.f / (sum + 1e-8f);
    // pass 3: weighted accumulate of hA rows
    float a0 = 0.f, a1 = 0.f, a2 = 0.f, a3 = 0.f;
    for (int j = beg; j < end; j++) {
        int d = dlist[j];
        float x = u + p1p[d];
        x = x > 0.f ? x : 0.01f * x;
        float coef = __expf(x - m) * inv;
        s16x4 h = *(const s16x4*)(hA + (size_t)d * D + lane * 4);
        a0 += coef * s2f(h[0]); a1 += coef * s2f(h[1]);
        a2 += coef * s2f(h[2]); a3 += coef * s2f(h[3]);
    }
    a0 = a0 > 0.f ? a0 : __expf(a0) - 1.f;
    a1 = a1 > 0.f ? a1 : __expf(a1) - 1.f;
    a2 = a2 > 0.f ? a2 : __expf(a2) - 1.f;
    a3 = a3 > 0.f ? a3 : __expf(a3) - 1.f;
    s16x4 o; o[0] = f2s(a0); o[1] = f2s(a1); o[2] = f2s(a2); o[3] = f2s(a3);
    *(s16x4*)(ctx + (size_t)w * D + lane * 4) = o;
}

// ---------------- fused GRU cell, MFMA, XCD-swizzled; OUTPUT FLOAT32 ----------------
__global__ __launch_bounds__(256) void gru_kernel(
    const short* __restrict__ ctx, const short* __restrict__ atom_bf,
    const float* __restrict__ atom_f,
    const short* __restrict__ W_ih, const short* __restrict__ W_hh,
    const float* __restrict__ b_ih, const float* __restrict__ b_hh,
    float* __restrict__ out, int N, int NB)
{
    // swizzle: all 16 col-blocks of an atom-group land on the same XCD (heuristic bi%8)
    int bi = blockIdx.x;
    int xcd = bi & 7, rest = bi >> 3;
    int cb = rest & 15, gh = rest >> 4;
    int gg = gh * 8 + xcd;
    if (gg >= NB) return;
    int wave = threadIdx.x >> 6, lane = threadIdx.x & 63;
    int quad = lane >> 4, l15 = lane & 15;
    int m0 = gg * 64 + wave * 16;
    int c0 = cb * 16;
    int arow = m0 + l15; if (arow > N - 1) arow = N - 1;
    const short* cp = ctx + (size_t)arow * D + quad * 8;
    const short* ap = atom_bf + (size_t)arow * D + quad * 8;
    const short* wi = W_ih + (size_t)(c0 + l15) * D + quad * 8;
    const short* wh = W_hh + (size_t)(c0 + l15) * D + quad * 8;
    f32x4 ir = {0,0,0,0}, iz = {0,0,0,0}, in_ = {0,0,0,0};
    f32x4 hr = {0,0,0,0}, hz = {0,0,0,0}, hn = {0,0,0,0};
    #pragma unroll
    for (int k = 0; k < D; k += 32) {
        bf16x8 a1 = *(const bf16x8*)(cp + k);
        bf16x8 a2 = *(const bf16x8*)(ap + k);
        bf16x8 bir = *(const bf16x8*)(wi + k);
        bf16x8 biz = *(const bf16x8*)(wi + 256 * D + k);
        bf16x8 bin = *(const bf16x8*)(wi + 512 * D + k);
        bf16x8 bhr = *(const bf16x8*)(wh + k);
        bf16x8 bhz = *(const bf16x8*)(wh + 256 * D + k);
        bf16x8 bhn = *(const bf16x8*)(wh + 512 * D + k);
        ir  = MFMA(a1, bir, ir, 0, 0, 0);
        iz  = MFMA(a1, biz, iz, 0, 0, 0);
        in_ = MFMA(a1, bin, in_, 0, 0, 0);
        hr  = MFMA(a2, bhr, hr, 0, 0, 0);
        hz  = MFMA(a2, bhz, hz, 0, 0, 0);
        hn  = MFMA(a2, bhn, hn, 0, 0, 0);
    }
    int col = c0 + l15;
    float bir_s = b_ih[col], biz_s = b_ih[col + 256], bin_s = b_ih[col + 512];
    float bhr_s = b_hh[col], bhz_s = b_hh[col + 256], bhn_s = b_hh[col + 512];
    #pragma unroll
    for (int r = 0; r < 4; r++) {
        int row = m0 + quad * 4 + r;
        if (row < N) {
            float rr = 1.f / (1.f + __expf(-(ir[r] + bir_s + hr[r] + bhr_s)));
            float zz = 1.f / (1.f + __expf(-(iz[r] + biz_s + hz[r] + bhz_s)));
            float nn = tanhf(in_[r] + bin_s + rr * (hn[r] + bhn_s));
            float at = atom_f[(size_t)row * D + col];
            out[(size_t)row * D + col] = (1.f - zz) * nn + zz * at;
        }
    }
}

extern "C" void kernel_launch(void* const* d_in, const int* in_sizes, int n_in,
                              void* d_out, int out_size, void* d_ws, size_t ws_size,
                              hipStream_t stream) {
    const float* atom    = (const float*)d_in[0];
    const int*   bond    = (const int*)d_in[1];
    const float* W_align = (const float*)d_in[2];
    const float* b_align = (const float*)d_in[3];
    const float* bn_a_g  = (const float*)d_in[4];
    const float* bn_a_b  = (const float*)d_in[5];
    const float* bn_a_m  = (const float*)d_in[6];
    const float* bn_a_v  = (const float*)d_in[7];
    const float* W_att   = (const float*)d_in[8];
    const float* b_att   = (const float*)d_in[9];
    const float* bn_t_g  = (const float*)d_in[10];
    const float* bn_t_b  = (const float*)d_in[11];
    const float* bn_t_m  = (const float*)d_in[12];
    const float* bn_t_v  = (const float*)d_in[13];
    const float* W_ih    = (const float*)d_in[14];
    const float* W_hh    = (const float*)d_in[15];
    const float* b_ih    = (const float*)d_in[16];
    const float* b_hh    = (const float*)d_in[17];

    int N = in_sizes[0] / D;
    int E = in_sizes[1] / 2;
    const int* src = bond;
    const int* dst = bond + E;

    char* w = (char*)d_ws;
    size_t o = 0;
    auto alloc = [&](size_t bytes) {
        void* p = w + o;
        o = (o + bytes + 255) & ~(size_t)255;
        return p;
    };
    int*   cnt     = (int*)alloc((size_t)N * 4);
    int*   cursor  = (int*)alloc((size_t)N * 4);
    int*   offv    = (int*)alloc((size_t)(N + 1) * 4);
    int*   dlist   = (int*)alloc((size_t)E * 4);
    float* p0p     = (float*)alloc((size_t)N * 4);
    float* p1p     = (float*)alloc((size_t)N * 4);
    short* hA      = (short*)alloc((size_t)N * D * 2);
    short* ctx     = (short*)alloc((size_t)N * D * 2);
    short* atom_bf = (short*)alloc((size_t)N * D * 2);
    short* Watt_bf = (short*)alloc((size_t)D * D * 2);
    short* Wih_bf  = (short*)alloc((size_t)3 * D * D * 2);
    short* Whh_bf  = (short*)alloc((size_t)3 * D * D * 2);

    int nA = N * D / 4, nW = D * D / 4, nG = 3 * D * D / 4;
    cvt_kernel<<<(nA + 255) / 256, 256, 0, stream>>>(atom, atom_bf, nA);
    cvt_kernel<<<(nW + 255) / 256, 256, 0, stream>>>(W_att, Watt_bf, nW);
    cvt_kernel<<<(nG + 255) / 256, 256, 0, stream>>>(W_ih, Wih_bf, nG);
    cvt_kernel<<<(nG + 255) / 256, 256, 0, stream>>>(W_hh, Whh_bf, nG);

    p0p1_kernel<<<((size_t)N * 64 + 255) / 256, 256, 0, stream>>>(
        atom, W_align, b_align, bn_a_g, bn_a_b, bn_a_m, bn_a_v, p0p, p1p, N);
    init_kernel<<<(N + 255) / 256, 256, 0, stream>>>(cnt, cursor, N);
    count_kernel<<<(E + 255) / 256, 256, 0, stream>>>(src, cnt, E);
    scan_kernel<<<1, 256, 0, stream>>>(cnt, offv, N);
    fill_kernel<<<(E + 255) / 256, 256, 0, stream>>>(src, dst, offv, cursor, dlist, E);

    int NB = (N + 63) / 64;            // 157 atom groups
    int GH = (NB + 7) / 8;             // groups per XCD
    hA_kernel<<<8 * 4 * GH, 256, 0, stream>>>(
        atom_bf, Watt_bf, b_att, bn_t_g, bn_t_b, bn_t_m, bn_t_v, hA, N, NB);
    agg_kernel<<<((size_t)N * 64 + 255) / 256, 256, 0, stream>>>(
        offv, dlist, p0p, p1p, hA, ctx, N);
    gru_kernel<<<8 * 16 * GH, 256, 0, stream>>>(
        ctx, atom_bf, atom, Wih_bf, Whh_bf, b_ih, b_hh, (float*)d_out, N, NB);
}

// Round 9
// 200.023 us; speedup vs baseline: 24.6102x; 1.3379x over previous
//
#include <hip/hip_runtime.h>
#include <hip/hip_bf16.h>

#define D 256

typedef __attribute__((ext_vector_type(8))) short bf16x8;
typedef __attribute__((ext_vector_type(4))) short s16x4;
typedef __attribute__((ext_vector_type(4))) float f32x4;

#define MFMA __builtin_amdgcn_mfma_f32_16x16x32_bf16

__device__ __forceinline__ float s2f(short u) {
    union { unsigned int i; float f; } c;
    c.i = ((unsigned int)(unsigned short)u) << 16;
    return c.f;
}
__device__ __forceinline__ short f2s(float f) {
    union { float f; unsigned int u; } c; c.f = f;
    unsigned int u = c.u;
    u += 0x7fffu + ((u >> 16) & 1u);
    return (short)(u >> 16);
}

// ---------------- fused f32 -> bf16 conversion of all 4 arrays ----------------
__global__ __launch_bounds__(256) void cvt_all_kernel(
    const float* __restrict__ atom, short* __restrict__ atom_bf, int nA,
    const float* __restrict__ Wa, short* __restrict__ Wa_bf, int nW,
    const float* __restrict__ Wi, short* __restrict__ Wi_bf,
    const float* __restrict__ Wh, short* __restrict__ Wh_bf, int nG)
{
    int i = blockIdx.x * 256 + threadIdx.x;
    const float* src; short* dst; int j = i;
    if (j < nA) { src = atom; dst = atom_bf; }
    else { j -= nA;
        if (j < nW) { src = Wa; dst = Wa_bf; }
        else { j -= nW;
            if (j < nG) { src = Wi; dst = Wi_bf; }
            else { j -= nG;
                if (j < nG) { src = Wh; dst = Wh_bf; }
                else return;
            }
        }
    }
    float4 v = ((const float4*)src)[j];
    s16x4 o; o[0] = f2s(v.x); o[1] = f2s(v.y); o[2] = f2s(v.z); o[3] = f2s(v.w);
    ((s16x4*)dst)[j] = o;
}

// ---------------- per-atom align projections with BN folded in ----------------
__global__ __launch_bounds__(256) void p0p1_kernel(
    const float* __restrict__ atom, const float* __restrict__ W_align,
    const float* __restrict__ b_align,
    const float* __restrict__ g, const float* __restrict__ bb,
    const float* __restrict__ mn, const float* __restrict__ vr,
    float* __restrict__ p0p, float* __restrict__ p1p, int N)
{
    int w = (blockIdx.x * blockDim.x + threadIdx.x) >> 6;
    int lane = threadIdx.x & 63;
    if (w >= N) return;
    float4 a  = *(const float4*)(atom + (size_t)w * D + lane * 4);
    float4 w0 = *(const float4*)(W_align + lane * 4);
    float4 w1 = *(const float4*)(W_align + D + lane * 4);
    float d0 = a.x * w0.x + a.y * w0.y + a.z * w0.z + a.w * w0.w;
    float d1 = a.x * w1.x + a.y * w1.y + a.z * w1.z + a.w * w1.w;
    #pragma unroll
    for (int o = 32; o > 0; o >>= 1) {
        d0 += __shfl_xor(d0, o, 64);
        d1 += __shfl_xor(d1, o, 64);
    }
    if (lane == 0) {
        float A = rsqrtf(vr[0] + 1e-6f) * g[0];
        p0p[w] = A * (d0 + b_align[0]) + bb[0] - A * mn[0];
        p1p[w] = A * d1;
    }
}

// ---------------- zero CSR scratch ----------------
__global__ __launch_bounds__(256) void init_kernel(int* cnt, int* cursor, int N) {
    int i = blockIdx.x * 256 + threadIdx.x;
    if (i < N) { cnt[i] = 0; cursor[i] = 0; }
}

// ---------------- histogram of src ----------------
__global__ __launch_bounds__(256) void count_kernel(const int* __restrict__ src, int* cnt, int E) {
    int e = blockIdx.x * 256 + threadIdx.x;
    if (e < E) atomicAdd(&cnt[src[e]], 1);
}

// ---------------- exclusive scan, serial-chunk + 1024-scan (single block) ----------------
__global__ __launch_bounds__(1024) void scan_kernel(const int* __restrict__ cnt, int* __restrict__ off, int N) {
    __shared__ int sums[1024];
    int t = threadIdx.x;
    int CH = (N + 1023) / 1024;
    int beg = t * CH;
    int end = beg + CH; if (end > N) end = N;
    int s = 0;
    for (int i = beg; i < end; i++) s += cnt[i];
    sums[t] = s;
    __syncthreads();
    for (int d = 1; d < 1024; d <<= 1) {
        int x = (t >= d) ? sums[t - d] : 0;
        __syncthreads();
        sums[t] += x;
        __syncthreads();
    }
    int run = (t > 0) ? sums[t - 1] : 0;
    for (int i = beg; i < end; i++) { off[i] = run; run += cnt[i]; }
    if (end == N) off[N] = run;
}

// ---------------- fill dst-valued edge lists ----------------
__global__ __launch_bounds__(256) void fill_kernel(const int* __restrict__ src, const int* __restrict__ dst,
                                                   const int* __restrict__ off, int* cursor, int* dlist, int E) {
    int e = blockIdx.x * 256 + threadIdx.x;
    if (e < E) {
        int s = src[e];
        int p = atomicAdd(&cursor[s], 1);
        dlist[off[s] + p] = dst[e];
    }
}

// ---------------- hA = BN(atom @ W_att^T + b_att), MFMA + LDS-staged B ----------------
// Block: 4 waves, 64 atoms x 64 cols. B tile (64 rows x 512B) in LDS, 528B pitch.
__global__ __launch_bounds__(256) void hA_kernel(
    const short* __restrict__ atom_bf, const short* __restrict__ W_bf,
    const float* __restrict__ bias,
    const float* __restrict__ g, const float* __restrict__ bb,
    const float* __restrict__ mn, const float* __restrict__ vr,
    short* __restrict__ hA, int N, int NB)
{
    __shared__ short Bs[64 * 264];       // 264 shorts = 528B pitch (2-way bank conflict only)
    int bi = blockIdx.x;
    int xcd = bi & 7, rest = bi >> 3;
    int cb = rest & 3, gh = rest >> 2;
    int gg = gh * 8 + xcd;
    if (gg >= NB) return;
    int c0 = cb * 64;
    int tid = threadIdx.x;
    // stage B: 64 rows x 32 chunks of 16B
    for (int c = tid; c < 64 * 32; c += 256) {
        int row = c >> 5, o16 = c & 31;
        bf16x8 v = *(const bf16x8*)(W_bf + (size_t)(c0 + row) * D + o16 * 8);
        *(bf16x8*)(&Bs[row * 264 + o16 * 8]) = v;
    }
    __syncthreads();

    int wave = tid >> 6, lane = tid & 63;
    int quad = lane >> 4, l15 = lane & 15;
    int m0 = gg * 64 + wave * 16;
    int arow = m0 + l15; if (arow > N - 1) arow = N - 1;
    const short* ap = atom_bf + (size_t)arow * D + quad * 8;
    const short* b0p = &Bs[(l15) * 264 + quad * 8];
    const short* b1p = &Bs[(16 + l15) * 264 + quad * 8];
    const short* b2p = &Bs[(32 + l15) * 264 + quad * 8];
    const short* b3p = &Bs[(48 + l15) * 264 + quad * 8];
    f32x4 ac0 = {0,0,0,0}, ac1 = {0,0,0,0}, ac2 = {0,0,0,0}, ac3 = {0,0,0,0};
    #pragma unroll
    for (int k = 0; k < D; k += 32) {
        bf16x8 a  = *(const bf16x8*)(ap + k);
        bf16x8 b0 = *(const bf16x8*)(b0p + k);
        bf16x8 b1 = *(const bf16x8*)(b1p + k);
        bf16x8 b2 = *(const bf16x8*)(b2p + k);
        bf16x8 b3 = *(const bf16x8*)(b3p + k);
        ac0 = MFMA(a, b0, ac0, 0, 0, 0);
        ac1 = MFMA(a, b1, ac1, 0, 0, 0);
        ac2 = MFMA(a, b2, ac2, 0, 0, 0);
        ac3 = MFMA(a, b3, ac3, 0, 0, 0);
    }
    f32x4 accs[4] = {ac0, ac1, ac2, ac3};
    #pragma unroll
    for (int t = 0; t < 4; t++) {
        int col = c0 + t * 16 + l15;
        float sc = rsqrtf(vr[col] + 1e-6f) * g[col];
        float sh = bb[col] - mn[col] * sc;
        float bi_ = bias[col];
        #pragma unroll
        for (int r = 0; r < 4; r++) {
            int row = m0 + quad * 4 + r;
            if (row < N) hA[(size_t)row * D + col] = f2s((accs[t][r] + bi_) * sc + sh);
        }
    }
}

// ---------------- fused score+softmax+aggregate (wave per atom), bf16 ctx out ----------------
__global__ __launch_bounds__(256) void agg_kernel(
    const int* __restrict__ off, const int* __restrict__ dlist,
    const float* __restrict__ p0p, const float* __restrict__ p1p,
    const short* __restrict__ hA, short* __restrict__ ctx, int N)
{
    int w = (blockIdx.x * blockDim.x + threadIdx.x) >> 6;
    int lane = threadIdx.x & 63;
    if (w >= N) return;
    int beg = off[w], end = off[w + 1];
    float u = p0p[w];
    float m = -INFINITY;
    for (int j = beg + lane; j < end; j += 64) {
        float x = u + p1p[dlist[j]];
        x = x > 0.f ? x : 0.01f * x;
        m = fmaxf(m, x);
    }
    #pragma unroll
    for (int o = 32; o > 0; o >>= 1) m = fmaxf(m, __shfl_xor(m, o, 64));
    float sum = 0.f;
    for (int j = beg + lane; j < end; j += 64) {
        float x = u + p1p[dlist[j]];
        x = x > 0.f ? x : 0.01f * x;
        sum += __expf(x - m);
    }
    #pragma unroll
    for (int o = 32; o > 0; o >>= 1) sum += __shfl_xor(sum, o, 64);
    float inv = 1.f / (sum + 1e-8f);
    // pass 3: two edges in parallel (lane halves), 16B row gathers
    int half = lane >> 5, l32 = lane & 31;
    float acc[8] = {0.f,0.f,0.f,0.f,0.f,0.f,0.f,0.f};
    for (int j = beg + half; j < end; j += 2) {
        int d = dlist[j];
        float x = u + p1p[d];
        x = x > 0.f ? x : 0.01f * x;
        float coef = __expf(x - m) * inv;
        bf16x8 h = *(const bf16x8*)(hA + (size_t)d * D + l32 * 8);
        #pragma unroll
        for (int i = 0; i < 8; i++) acc[i] += coef * s2f(h[i]);
    }
    #pragma unroll
    for (int i = 0; i < 8; i++) acc[i] += __shfl_xor(acc[i], 32, 64);
    if (half == 0) {
        bf16x8 o;
        #pragma unroll
        for (int i = 0; i < 8; i++) {
            float v = acc[i];
            v = v > 0.f ? v : __expf(v) - 1.f;
            o[i] = f2s(v);
        }
        *(bf16x8*)(ctx + (size_t)w * D + l32 * 8) = o;
    }
}

// ---------------- fused GRU cell, MFMA + LDS-staged B; OUTPUT FLOAT32 ----------------
// Block: 4 waves, 64 atoms x 16 cols. B tile = 6 gates x 16 rows x 512B in LDS (528B pitch).
__global__ __launch_bounds__(256) void gru_kernel(
    const short* __restrict__ ctx, const short* __restrict__ atom_bf,
    const float* __restrict__ atom_f,
    const short* __restrict__ W_ih, const short* __restrict__ W_hh,
    const float* __restrict__ b_ih, const float* __restrict__ b_hh,
    float* __restrict__ out, int N, int NB)
{
    __shared__ short Bs[6 * 16 * 264];   // 49.5KB
    int bi = blockIdx.x;
    int xcd = bi & 7, rest = bi >> 3;
    int cb = rest & 15, gh = rest >> 4;
    int gg = gh * 8 + xcd;
    if (gg >= NB) return;
    int c0 = cb * 16;
    int tid = threadIdx.x;
    // stage B: 96 rows (6 gates x 16) x 32 chunks of 16B
    for (int c = tid; c < 96 * 32; c += 256) {
        int row = c >> 5, o16 = c & 31;
        int gate = row >> 4, r = row & 15;
        const short* srcp = (gate < 3)
            ? W_ih + (size_t)(gate * 256 + c0 + r) * D + o16 * 8
            : W_hh + (size_t)((gate - 3) * 256 + c0 + r) * D + o16 * 8;
        bf16x8 v = *(const bf16x8*)srcp;
        *(bf16x8*)(&Bs[row * 264 + o16 * 8]) = v;
    }
    __syncthreads();

    int wave = tid >> 6, lane = tid & 63;
    int quad = lane >> 4, l15 = lane & 15;
    int m0 = gg * 64 + wave * 16;
    int arow = m0 + l15; if (arow > N - 1) arow = N - 1;
    const short* cp = ctx + (size_t)arow * D + quad * 8;
    const short* ap = atom_bf + (size_t)arow * D + quad * 8;
    const short* lb = &Bs[l15 * 264 + quad * 8];
    f32x4 ir = {0,0,0,0}, iz = {0,0,0,0}, in_ = {0,0,0,0};
    f32x4 hr = {0,0,0,0}, hz = {0,0,0,0}, hn = {0,0,0,0};
    #pragma unroll
    for (int k = 0; k < D; k += 32) {
        bf16x8 a1 = *(const bf16x8*)(cp + k);
        bf16x8 a2 = *(const bf16x8*)(ap + k);
        bf16x8 bir = *(const bf16x8*)(lb + 0 * 4224 + k);
        bf16x8 biz = *(const bf16x8*)(lb + 1 * 4224 + k);
        bf16x8 bin = *(const bf16x8*)(lb + 2 * 4224 + k);
        bf16x8 bhr = *(const bf16x8*)(lb + 3 * 4224 + k);
        bf16x8 bhz = *(const bf16x8*)(lb + 4 * 4224 + k);
        bf16x8 bhn = *(const bf16x8*)(lb + 5 * 4224 + k);
        ir  = MFMA(a1, bir, ir, 0, 0, 0);
        iz  = MFMA(a1, biz, iz, 0, 0, 0);
        in_ = MFMA(a1, bin, in_, 0, 0, 0);
        hr  = MFMA(a2, bhr, hr, 0, 0, 0);
        hz  = MFMA(a2, bhz, hz, 0, 0, 0);
        hn  = MFMA(a2, bhn, hn, 0, 0, 0);
    }
    int col = c0 + l15;
    float bir_s = b_ih[col], biz_s = b_ih[col + 256], bin_s = b_ih[col + 512];
    float bhr_s = b_hh[col], bhz_s = b_hh[col + 256], bhn_s = b_hh[col + 512];
    #pragma unroll
    for (int r = 0; r < 4; r++) {
        int row = m0 + quad * 4 + r;
        if (row < N) {
            float rr = 1.f / (1.f + __expf(-(ir[r] + bir_s + hr[r] + bhr_s)));
            float zz = 1.f / (1.f + __expf(-(iz[r] + biz_s + hz[r] + bhz_s)));
            float nn = tanhf(in_[r] + bin_s + rr * (hn[r] + bhn_s));
            float at = atom_f[(size_t)row * D + col];
            out[(size_t)row * D + col] = (1.f - zz) * nn + zz * at;
        }
    }
}

extern "C" void kernel_launch(void* const* d_in, const int* in_sizes, int n_in,
                              void* d_out, int out_size, void* d_ws, size_t ws_size,
                              hipStream_t stream) {
    const float* atom    = (const float*)d_in[0];
    const int*   bond    = (const int*)d_in[1];
    const float* W_align = (const float*)d_in[2];
    const float* b_align = (const float*)d_in[3];
    const float* bn_a_g  = (const float*)d_in[4];
    const float* bn_a_b  = (const float*)d_in[5];
    const float* bn_a_m  = (const float*)d_in[6];
    const float* bn_a_v  = (const float*)d_in[7];
    const float* W_att   = (const float*)d_in[8];
    const float* b_att   = (const float*)d_in[9];
    const float* bn_t_g  = (const float*)d_in[10];
    const float* bn_t_b  = (const float*)d_in[11];
    const float* bn_t_m  = (const float*)d_in[12];
    const float* bn_t_v  = (const float*)d_in[13];
    const float* W_ih    = (const float*)d_in[14];
    const float* W_hh    = (const float*)d_in[15];
    const float* b_ih    = (const float*)d_in[16];
    const float* b_hh    = (const float*)d_in[17];

    int N = in_sizes[0] / D;
    int E = in_sizes[1] / 2;
    const int* src = bond;
    const int* dst = bond + E;

    char* w = (char*)d_ws;
    size_t o = 0;
    auto alloc = [&](size_t bytes) {
        void* p = w + o;
        o = (o + bytes + 255) & ~(size_t)255;
        return p;
    };
    int*   cnt     = (int*)alloc((size_t)N * 4);
    int*   cursor  = (int*)alloc((size_t)N * 4);
    int*   offv    = (int*)alloc((size_t)(N + 1) * 4);
    int*   dlist   = (int*)alloc((size_t)E * 4);
    float* p0p     = (float*)alloc((size_t)N * 4);
    float* p1p     = (float*)alloc((size_t)N * 4);
    short* hA      = (short*)alloc((size_t)N * D * 2);
    short* ctx     = (short*)alloc((size_t)N * D * 2);
    short* atom_bf = (short*)alloc((size_t)N * D * 2);
    short* Watt_bf = (short*)alloc((size_t)D * D * 2);
    short* Wih_bf  = (short*)alloc((size_t)3 * D * D * 2);
    short* Whh_bf  = (short*)alloc((size_t)3 * D * D * 2);

    int nA = N * D / 4, nW = D * D / 4, nG = 3 * D * D / 4;
    int nTot = nA + nW + 2 * nG;
    cvt_all_kernel<<<(nTot + 255) / 256, 256, 0, stream>>>(
        atom, atom_bf, nA, W_att, Watt_bf, nW, W_ih, Wih_bf, W_hh, Whh_bf, nG);

    p0p1_kernel<<<((size_t)N * 64 + 255) / 256, 256, 0, stream>>>(
        atom, W_align, b_align, bn_a_g, bn_a_b, bn_a_m, bn_a_v, p0p, p1p, N);
    init_kernel<<<(N + 255) / 256, 256, 0, stream>>>(cnt, cursor, N);
    count_kernel<<<(E + 255) / 256, 256, 0, stream>>>(src, cnt, E);
    scan_kernel<<<1, 1024, 0, stream>>>(cnt, offv, N);
    fill_kernel<<<(E + 255) / 256, 256, 0, stream>>>(src, dst, offv, cursor, dlist, E);

    int NB = (N + 63) / 64;            // 157 atom groups
    int GH = (NB + 7) / 8;             // groups per XCD
    hA_kernel<<<8 * 4 * GH, 256, 0, stream>>>(
        atom_bf, Watt_bf, b_att, bn_t_g, bn_t_b, bn_t_m, bn_t_v, hA, N, NB);
    agg_kernel<<<((size_t)N * 64 + 255) / 256, 256, 0, stream>>>(
        offv, dlist, p0p, p1p, hA, ctx, N);
    gru_kernel<<<8 * 16 * GH, 256, 0, stream>>>(
        ctx, atom_bf, atom, Wih_bf, Whh_bf, b_ih, b_hh, (float*)d_out, N, NB);
}